// Round 2
// baseline (837.655 us; speedup 1.0000x reference)
//
#include <hip/hip_runtime.h>

typedef short bf16x8 __attribute__((ext_vector_type(8)));
typedef float floatx4 __attribute__((ext_vector_type(4)));

__device__ __forceinline__ unsigned short f2bf(float f) {
    unsigned int u = __float_as_uint(f);
    unsigned int r = u + 0x7fffu + ((u >> 16) & 1u);   // RNE
    return (unsigned short)(r >> 16);
}
__device__ __forceinline__ float bf2f(unsigned int u) {
    return __uint_as_float(u << 16);
}

// WT[c][k] = W[k][c] as bf16. c in [0,640): c<512 -> basis[b=c>>7][k][o=c&127],
// c>=512 -> loop_weight[k][c-512]. Contiguous-k 16B B-fragment loads.
__global__ __launch_bounds__(256) void prep_wt(
    const float* __restrict__ basis,   // (4,128,128) f32
    const float* __restrict__ loopw,   // (128,128) f32
    unsigned short* __restrict__ WT)   // (640,128) bf16
{
    int idx = blockIdx.x * 256 + threadIdx.x;   // 0..81919
    int k = idx & 127;
    int c = idx >> 7;
    float v;
    if (c < 512) {
        int b = c >> 7;
        int o = c & 127;
        v = basis[(b * 128 + k) * 128 + o];
    } else {
        v = loopw[k * 128 + (c - 512)];
    }
    WT[c * 128 + k] = f2bf(v);
}

// (N,128) @ (128,640) bf16-MFMA GEMM (f32 h converted inline).
// Block = 4 waves = 64 rows; grid y = 5 slabs of 128 cols.
// proj (cols 0..511) stored bf16; loop (cols 512..639) stored f32.
__global__ __launch_bounds__(256) void proj_gemm(
    const float* __restrict__ h,            // (N,128) f32
    const unsigned short* __restrict__ WT,  // (640,128) bf16
    unsigned short* __restrict__ proj,      // (N,512) bf16 = [n][b][o]
    float* __restrict__ loopbuf,            // (N,128) f32
    int N)
{
    const int wave = threadIdx.x >> 6;
    const int lane = threadIdx.x & 63;
    const int quad = lane >> 4;
    const int low  = lane & 15;
    const int m0 = blockIdx.x * 64 + wave * 16;
    const int c0 = blockIdx.y * 128;

    // A fragment: lane holds A[m=low][k=quad*8+j], j=0..7
    int row = m0 + low;
    if (row >= N) row = N - 1;            // clamp for load; store is guarded
    const float* hp = h + (size_t)row * 128 + quad * 8;
    bf16x8 afrag[4];
#pragma unroll
    for (int kk = 0; kk < 4; ++kk) {
        float4 x0 = *(const float4*)(hp + kk * 32);
        float4 x1 = *(const float4*)(hp + kk * 32 + 4);
        bf16x8 a;
        a[0] = (short)f2bf(x0.x); a[1] = (short)f2bf(x0.y);
        a[2] = (short)f2bf(x0.z); a[3] = (short)f2bf(x0.w);
        a[4] = (short)f2bf(x1.x); a[5] = (short)f2bf(x1.y);
        a[6] = (short)f2bf(x1.z); a[7] = (short)f2bf(x1.w);
        afrag[kk] = a;
    }

    floatx4 acc[8];
#pragma unroll
    for (int t = 0; t < 8; ++t) acc[t] = (floatx4){0.f, 0.f, 0.f, 0.f};

#pragma unroll
    for (int t = 0; t < 8; ++t) {
        const int col = c0 + t * 16 + low;
        const bf16x8* bp = (const bf16x8*)(WT + (size_t)col * 128 + quad * 8);
#pragma unroll
        for (int kk = 0; kk < 4; ++kk) {
            acc[t] = __builtin_amdgcn_mfma_f32_16x16x32_bf16(afrag[kk], bp[kk * 4], acc[t], 0, 0, 0);
        }
    }

    // C/D layout: col = lane&15, row = (lane>>4)*4 + reg
    const int rbase = m0 + quad * 4;
#pragma unroll
    for (int t = 0; t < 8; ++t) {
        const int c = c0 + t * 16 + low;
#pragma unroll
        for (int r = 0; r < 4; ++r) {
            int rr = rbase + r;
            if (rr >= N) continue;
            if (c < 512) proj[(size_t)rr * 512 + c] = f2bf(acc[t][r]);
            else         loopbuf[(size_t)rr * 128 + (c - 512)] = acc[t][r];
        }
    }
}

// One wave per edge: gather proj[src] (1KB bf16, contiguous), mix by relation
// coeffs (f32), scatter-add f32 into agg[dst]. Lane handles 2 outputs.
__global__ __launch_bounds__(256) void edge_scatter(
    const unsigned short* __restrict__ proj,
    const int* __restrict__ src, const int* __restrict__ dst,
    const int* __restrict__ rel, const float* __restrict__ coeff,
    float* __restrict__ agg, int E)
{
    const int e = blockIdx.x * 4 + (threadIdx.x >> 6);
    if (e >= E) return;
    const int lane = threadIdx.x & 63;
    const int s = src[e];
    const int d = dst[e];
    const int r = rel[e];
    const float4 c = *(const float4*)(coeff + (size_t)r * 4);
    const unsigned short* p = proj + (size_t)s * 512 + lane * 2;
    unsigned int v0 = *(const unsigned int*)(p);
    unsigned int v1 = *(const unsigned int*)(p + 128);
    unsigned int v2 = *(const unsigned int*)(p + 256);
    unsigned int v3 = *(const unsigned int*)(p + 384);
    float m0 = c.x * bf2f(v0 & 0xffffu) + c.y * bf2f(v1 & 0xffffu)
             + c.z * bf2f(v2 & 0xffffu) + c.w * bf2f(v3 & 0xffffu);
    float m1 = c.x * bf2f(v0 >> 16) + c.y * bf2f(v1 >> 16)
             + c.z * bf2f(v2 >> 16) + c.w * bf2f(v3 >> 16);
    float* ap = agg + (size_t)d * 128 + lane * 2;
    unsafeAtomicAdd(ap, m0);
    unsafeAtomicAdd(ap + 1, m1);
}

// out = relu(agg*norm + loop), f32 out, one thread per 2 outputs.
__global__ __launch_bounds__(256) void finalize(
    const float* __restrict__ agg,
    const float* __restrict__ norm,
    const float* __restrict__ loopbuf,
    float* __restrict__ out, int N)
{
    int idx = blockIdx.x * 256 + threadIdx.x;
    if (idx >= N * 64) return;
    int n = idx >> 6;
    int op = (idx & 63) * 2;
    float nm = norm[n];
    float2 a = *(const float2*)(agg + (size_t)n * 128 + op);
    float2 l = *(const float2*)(loopbuf + (size_t)n * 128 + op);
    float o0 = a.x * nm + l.x;
    float o1 = a.y * nm + l.y;
    o0 = o0 > 0.f ? o0 : 0.f;
    o1 = o1 > 0.f ? o1 : 0.f;
    *(float2*)(out + (size_t)n * 128 + op) = make_float2(o0, o1);
}

extern "C" void kernel_launch(void* const* d_in, const int* in_sizes, int n_in,
                              void* d_out, int out_size, void* d_ws, size_t ws_size,
                              hipStream_t stream)
{
    const float* h     = (const float*)d_in[0];
    const float* norm  = (const float*)d_in[1];
    const int*   src   = (const int*)d_in[2];
    const int*   dst   = (const int*)d_in[3];
    const int*   rel   = (const int*)d_in[4];
    const float* basis = (const float*)d_in[5];
    const float* coeff = (const float*)d_in[6];
    const float* loopw = (const float*)d_in[7];
    float* out = (float*)d_out;

    const int N = in_sizes[1];   // 50000
    const int E = in_sizes[2];   // 800000

    char* ws = (char*)d_ws;
    size_t off = 0;
    auto walloc = [&](size_t bytes) -> char* {
        char* p = ws + off;
        off = (off + bytes + 255) & ~(size_t)255;
        return p;
    };
    unsigned short* proj    = (unsigned short*)walloc((size_t)N * 512 * 2);  // 51.2 MB bf16
    float*          agg     = (float*)walloc((size_t)N * 128 * 4);           // 25.6 MB f32
    float*          loopbuf = (float*)walloc((size_t)N * 128 * 4);           // 25.6 MB f32
    unsigned short* WT      = (unsigned short*)walloc(640 * 128 * 2);        // 164 KB bf16

    hipMemsetAsync(agg, 0, (size_t)N * 128 * 4, stream);
    prep_wt<<<320, 256, 0, stream>>>(basis, loopw, WT);
    proj_gemm<<<dim3((N + 63) / 64, 5), 256, 0, stream>>>(h, WT, proj, loopbuf, N);
    edge_scatter<<<(E + 3) / 4, 256, 0, stream>>>(proj, src, dst, rel, coeff, agg, E);
    finalize<<<(N * 64 + 255) / 256, 256, 0, stream>>>(agg, norm, loopbuf, out, N);
}

// Round 3
// 369.751 us; speedup vs baseline: 2.2655x; 2.2655x over previous
//
#include <hip/hip_runtime.h>

typedef short bf16x8 __attribute__((ext_vector_type(8)));
typedef float floatx4 __attribute__((ext_vector_type(4)));

__device__ __forceinline__ unsigned short f2bf(float f) {
    unsigned int u = __float_as_uint(f);
    unsigned int r = u + 0x7fffu + ((u >> 16) & 1u);   // RNE
    return (unsigned short)(r >> 16);
}
__device__ __forceinline__ float bf2f(unsigned int u) {
    return __uint_as_float(u << 16);
}

// WT[c][k] = W[k][c] as bf16. c<512 -> basis[b=c>>7][k][o=c&127]; c>=512 -> loop_weight.
__global__ __launch_bounds__(256) void prep_wt(
    const float* __restrict__ basis,   // (4,128,128) f32
    const float* __restrict__ loopw,   // (128,128) f32
    unsigned short* __restrict__ WT)   // (640,128) bf16
{
    int idx = blockIdx.x * 256 + threadIdx.x;   // 0..81919
    int k = idx & 127;
    int c = idx >> 7;
    float v;
    if (c < 512) {
        int b = c >> 7;
        int o = c & 127;
        v = basis[(b * 128 + k) * 128 + o];
    } else {
        v = loopw[k * 128 + (c - 512)];
    }
    WT[c * 128 + k] = f2bf(v);
}

// (N,128)@(128,640) bf16-MFMA GEMM. proj cols 0..511 bf16; loop cols 512..639 f32.
__global__ __launch_bounds__(256) void proj_gemm(
    const float* __restrict__ h,            // (N,128) f32
    const unsigned short* __restrict__ WT,  // (640,128) bf16
    unsigned short* __restrict__ proj,      // (N,512) bf16 = [n][b][o]
    float* __restrict__ loopbuf,            // (N,128) f32
    int N)
{
    const int wave = threadIdx.x >> 6;
    const int lane = threadIdx.x & 63;
    const int quad = lane >> 4;
    const int low  = lane & 15;
    const int m0 = blockIdx.x * 64 + wave * 16;
    const int c0 = blockIdx.y * 128;

    int row = m0 + low;
    if (row >= N) row = N - 1;            // clamp for load; store is guarded
    const float* hp = h + (size_t)row * 128 + quad * 8;
    bf16x8 afrag[4];
#pragma unroll
    for (int kk = 0; kk < 4; ++kk) {
        float4 x0 = *(const float4*)(hp + kk * 32);
        float4 x1 = *(const float4*)(hp + kk * 32 + 4);
        bf16x8 a;
        a[0] = (short)f2bf(x0.x); a[1] = (short)f2bf(x0.y);
        a[2] = (short)f2bf(x0.z); a[3] = (short)f2bf(x0.w);
        a[4] = (short)f2bf(x1.x); a[5] = (short)f2bf(x1.y);
        a[6] = (short)f2bf(x1.z); a[7] = (short)f2bf(x1.w);
        afrag[kk] = a;
    }

    floatx4 acc[8];
#pragma unroll
    for (int t = 0; t < 8; ++t) acc[t] = (floatx4){0.f, 0.f, 0.f, 0.f};

#pragma unroll
    for (int t = 0; t < 8; ++t) {
        const int col = c0 + t * 16 + low;
        const bf16x8* bp = (const bf16x8*)(WT + (size_t)col * 128 + quad * 8);
#pragma unroll
        for (int kk = 0; kk < 4; ++kk) {
            acc[t] = __builtin_amdgcn_mfma_f32_16x16x32_bf16(afrag[kk], bp[kk * 4], acc[t], 0, 0, 0);
        }
    }

    const int rbase = m0 + quad * 4;   // C/D: col=lane&15, row=(lane>>4)*4+reg
#pragma unroll
    for (int t = 0; t < 8; ++t) {
        const int c = c0 + t * 16 + low;
#pragma unroll
        for (int r = 0; r < 4; ++r) {
            int rr = rbase + r;
            if (rr >= N) continue;
            if (c < 512) proj[(size_t)rr * 512 + c] = f2bf(acc[t][r]);
            else         loopbuf[(size_t)rr * 128 + (c - 512)] = acc[t][r];
        }
    }
}

// ---- counting sort by dst ----

__global__ __launch_bounds__(256) void hist(
    const int* __restrict__ dst, int* __restrict__ cnt, int E)
{
    int e = blockIdx.x * 256 + threadIdx.x;
    if (e < E) atomicAdd(&cnt[dst[e]], 1);
}

__global__ __launch_bounds__(256) void scan1(
    const int* __restrict__ cnt, int* __restrict__ bsum, int N)
{
    __shared__ int s[256];
    int i = blockIdx.x * 256 + threadIdx.x;
    int t = threadIdx.x;
    s[t] = (i < N) ? cnt[i] : 0;
    __syncthreads();
    for (int o = 128; o > 0; o >>= 1) {
        if (t < o) s[t] += s[t + o];
        __syncthreads();
    }
    if (t == 0) bsum[blockIdx.x] = s[0];
}

__global__ __launch_bounds__(256) void scan2(int* __restrict__ bsum, int nb)
{
    __shared__ int s[256];
    int t = threadIdx.x;
    int v = (t < nb) ? bsum[t] : 0;
    s[t] = v;
    __syncthreads();
    for (int o = 1; o < 256; o <<= 1) {
        int x = (t >= o) ? s[t - o] : 0;
        __syncthreads();
        s[t] += x;
        __syncthreads();
    }
    if (t < nb) bsum[t] = s[t] - v;   // exclusive
}

__global__ __launch_bounds__(256) void scan3(
    const int* __restrict__ cnt, const int* __restrict__ bsum,
    int* __restrict__ rowptr, int* __restrict__ cursor, int N, int E)
{
    __shared__ int s[256];
    int i = blockIdx.x * 256 + threadIdx.x;
    int t = threadIdx.x;
    int v = (i < N) ? cnt[i] : 0;
    s[t] = v;
    __syncthreads();
    for (int o = 1; o < 256; o <<= 1) {
        int x = (t >= o) ? s[t - o] : 0;
        __syncthreads();
        s[t] += x;
        __syncthreads();
    }
    int excl = s[t] - v + bsum[blockIdx.x];
    if (i < N) { rowptr[i] = excl; cursor[i] = excl; }
    if (i == N - 1) rowptr[N] = E;
}

__global__ __launch_bounds__(256) void scatter_sort(
    const int* __restrict__ src, const int* __restrict__ dst,
    const int* __restrict__ rel, int* __restrict__ cursor,
    int2* __restrict__ sedge, int E)
{
    int e = blockIdx.x * 256 + threadIdx.x;
    if (e >= E) return;
    int d = dst[e];
    int pos = atomicAdd(&cursor[d], 1);
    sedge[pos] = make_int2(src[e], rel[e]);
}

// One wave per dst node: walk its edge segment, gather proj[src] (bf16 1KB,
// coalesced dword loads), accumulate 2 f32/lane, fuse relu(acc*norm + loop).
__global__ __launch_bounds__(256) void aggregate(
    const unsigned short* __restrict__ proj,
    const int* __restrict__ rowptr,
    const int2* __restrict__ sedge,
    const float* __restrict__ coeff,
    const float* __restrict__ norm,
    const float* __restrict__ loopbuf,
    float* __restrict__ out, int N)
{
    const int wave = threadIdx.x >> 6;
    const int lane = threadIdx.x & 63;
    const int d = blockIdx.x * 4 + wave;
    if (d >= N) return;
    const int start = rowptr[d];
    const int end   = rowptr[d + 1];

    float a0 = 0.f, a1 = 0.f;
    int i = start;
    for (; i + 2 <= end; i += 2) {
        int2 e0 = sedge[i];
        int2 e1 = sedge[i + 1];
        const unsigned int* q0 = (const unsigned int*)(proj + (size_t)e0.x * 512);
        const unsigned int* q1 = (const unsigned int*)(proj + (size_t)e1.x * 512);
        float4 c0 = *(const float4*)(coeff + (size_t)e0.y * 4);
        float4 c1 = *(const float4*)(coeff + (size_t)e1.y * 4);
        unsigned int u0 = q0[lane],       u1 = q0[lane + 64];
        unsigned int u2 = q0[lane + 128], u3 = q0[lane + 192];
        unsigned int w0 = q1[lane],       w1 = q1[lane + 64];
        unsigned int w2 = q1[lane + 128], w3 = q1[lane + 192];
        a0 += c0.x * bf2f(u0 & 0xffffu) + c0.y * bf2f(u1 & 0xffffu)
            + c0.z * bf2f(u2 & 0xffffu) + c0.w * bf2f(u3 & 0xffffu);
        a1 += c0.x * bf2f(u0 >> 16) + c0.y * bf2f(u1 >> 16)
            + c0.z * bf2f(u2 >> 16) + c0.w * bf2f(u3 >> 16);
        a0 += c1.x * bf2f(w0 & 0xffffu) + c1.y * bf2f(w1 & 0xffffu)
            + c1.z * bf2f(w2 & 0xffffu) + c1.w * bf2f(w3 & 0xffffu);
        a1 += c1.x * bf2f(w0 >> 16) + c1.y * bf2f(w1 >> 16)
            + c1.z * bf2f(w2 >> 16) + c1.w * bf2f(w3 >> 16);
    }
    if (i < end) {
        int2 e0 = sedge[i];
        const unsigned int* q0 = (const unsigned int*)(proj + (size_t)e0.x * 512);
        float4 c0 = *(const float4*)(coeff + (size_t)e0.y * 4);
        unsigned int u0 = q0[lane],       u1 = q0[lane + 64];
        unsigned int u2 = q0[lane + 128], u3 = q0[lane + 192];
        a0 += c0.x * bf2f(u0 & 0xffffu) + c0.y * bf2f(u1 & 0xffffu)
            + c0.z * bf2f(u2 & 0xffffu) + c0.w * bf2f(u3 & 0xffffu);
        a1 += c0.x * bf2f(u0 >> 16) + c0.y * bf2f(u1 >> 16)
            + c0.z * bf2f(u2 >> 16) + c0.w * bf2f(u3 >> 16);
    }

    const float nm = norm[d];
    float2 l = *(const float2*)(loopbuf + (size_t)d * 128 + lane * 2);
    float o0 = fmaxf(a0 * nm + l.x, 0.f);
    float o1 = fmaxf(a1 * nm + l.y, 0.f);
    *(float2*)(out + (size_t)d * 128 + lane * 2) = make_float2(o0, o1);
}

extern "C" void kernel_launch(void* const* d_in, const int* in_sizes, int n_in,
                              void* d_out, int out_size, void* d_ws, size_t ws_size,
                              hipStream_t stream)
{
    const float* h     = (const float*)d_in[0];
    const float* norm  = (const float*)d_in[1];
    const int*   src   = (const int*)d_in[2];
    const int*   dst   = (const int*)d_in[3];
    const int*   rel   = (const int*)d_in[4];
    const float* basis = (const float*)d_in[5];
    const float* coeff = (const float*)d_in[6];
    const float* loopw = (const float*)d_in[7];
    float* out = (float*)d_out;

    const int N = in_sizes[1];   // 50000
    const int E = in_sizes[2];   // 800000
    const int NB = (N + 255) / 256;   // scan blocks (196 <= 256)

    char* ws = (char*)d_ws;
    size_t off = 0;
    auto walloc = [&](size_t bytes) -> char* {
        char* p = ws + off;
        off = (off + bytes + 255) & ~(size_t)255;
        return p;
    };
    unsigned short* proj    = (unsigned short*)walloc((size_t)N * 512 * 2);  // 51.2 MB
    float*          loopbuf = (float*)walloc((size_t)N * 128 * 4);           // 25.6 MB
    unsigned short* WT      = (unsigned short*)walloc(640 * 128 * 2);        // 164 KB
    int*            cnt     = (int*)walloc((size_t)N * 4);
    int*            rowptr  = (int*)walloc((size_t)(N + 1) * 4);
    int*            cursor  = (int*)walloc((size_t)N * 4);
    int*            bsum    = (int*)walloc((size_t)NB * 4);
    int2*           sedge   = (int2*)walloc((size_t)E * 8);                  // 6.4 MB

    hipMemsetAsync(cnt, 0, (size_t)N * 4, stream);
    prep_wt<<<320, 256, 0, stream>>>(basis, loopw, WT);
    proj_gemm<<<dim3((N + 63) / 64, 5), 256, 0, stream>>>(h, WT, proj, loopbuf, N);
    hist<<<(E + 255) / 256, 256, 0, stream>>>(dst, cnt, E);
    scan1<<<NB, 256, 0, stream>>>(cnt, bsum, N);
    scan2<<<1, 256, 0, stream>>>(bsum, NB);
    scan3<<<NB, 256, 0, stream>>>(cnt, bsum, rowptr, cursor, N, E);
    scatter_sort<<<(E + 255) / 256, 256, 0, stream>>>(src, dst, rel, cursor, sedge, E);
    aggregate<<<(N + 3) / 4, 256, 0, stream>>>(proj, rowptr, sedge, coeff, norm, loopbuf, out, N);
}

// Round 4
// 329.252 us; speedup vs baseline: 2.5441x; 1.1230x over previous
//
#include <hip/hip_runtime.h>

typedef short bf16x8 __attribute__((ext_vector_type(8)));
typedef float floatx4 __attribute__((ext_vector_type(4)));

__device__ __forceinline__ unsigned short f2bf(float f) {
    unsigned int u = __float_as_uint(f);
    unsigned int r = u + 0x7fffu + ((u >> 16) & 1u);   // RNE
    return (unsigned short)(r >> 16);
}
__device__ __forceinline__ float bf2f(unsigned int u) {
    return __uint_as_float(u << 16);
}

// h (N,128) f32 -> h_bf (N,128) bf16, one thread per 2 elements.
__global__ __launch_bounds__(256) void conv_h(
    const float* __restrict__ h, unsigned short* __restrict__ hbf, int N)
{
    int idx = blockIdx.x * 256 + threadIdx.x;
    if (idx >= N * 64) return;
    float2 v = *(const float2*)(h + (size_t)idx * 2);
    unsigned int pack = (unsigned int)f2bf(v.x) | ((unsigned int)f2bf(v.y) << 16);
    *(unsigned int*)(hbf + (size_t)idx * 2) = pack;
}

// WT2[col][k] bf16, col in [0,128), k in [0,640):
//   k<512 -> basis[b=k>>7][i=k&127][col];  k>=512 -> loop_weight[k-512][col].
// Contiguous-k 16B B-fragment loads for the K=640 final GEMM.
__global__ __launch_bounds__(256) void prep_wt2(
    const float* __restrict__ basis,   // (4,128,128) f32
    const float* __restrict__ loopw,   // (128,128) f32
    unsigned short* __restrict__ WT2)  // (128,640) bf16
{
    int c = blockIdx.x;                 // 128 blocks, one per col
    for (int k = threadIdx.x; k < 640; k += 256) {
        float v;
        if (k < 512) v = basis[(size_t)k * 128 + c];        // ((k>>7)*128+(k&127))*128+c
        else         v = loopw[(size_t)(k - 512) * 128 + c];
        WT2[(size_t)c * 640 + k] = f2bf(v);
    }
}

// ---- counting sort by dst ----

__global__ __launch_bounds__(256) void hist(
    const int* __restrict__ dst, int* __restrict__ cnt, int E)
{
    int e = blockIdx.x * 256 + threadIdx.x;
    if (e < E) atomicAdd(&cnt[dst[e]], 1);
}

__global__ __launch_bounds__(256) void scan1(
    const int* __restrict__ cnt, int* __restrict__ bsum, int N)
{
    __shared__ int s[256];
    int i = blockIdx.x * 256 + threadIdx.x;
    int t = threadIdx.x;
    s[t] = (i < N) ? cnt[i] : 0;
    __syncthreads();
    for (int o = 128; o > 0; o >>= 1) {
        if (t < o) s[t] += s[t + o];
        __syncthreads();
    }
    if (t == 0) bsum[blockIdx.x] = s[0];
}

__global__ __launch_bounds__(256) void scan2(int* __restrict__ bsum, int nb)
{
    __shared__ int s[256];
    int t = threadIdx.x;
    int v = (t < nb) ? bsum[t] : 0;
    s[t] = v;
    __syncthreads();
    for (int o = 1; o < 256; o <<= 1) {
        int x = (t >= o) ? s[t - o] : 0;
        __syncthreads();
        s[t] += x;
        __syncthreads();
    }
    if (t < nb) bsum[t] = s[t] - v;   // exclusive
}

__global__ __launch_bounds__(256) void scan3(
    const int* __restrict__ cnt, const int* __restrict__ bsum,
    int* __restrict__ rowptr, int* __restrict__ cursor, int N, int E)
{
    __shared__ int s[256];
    int i = blockIdx.x * 256 + threadIdx.x;
    int t = threadIdx.x;
    int v = (i < N) ? cnt[i] : 0;
    s[t] = v;
    __syncthreads();
    for (int o = 1; o < 256; o <<= 1) {
        int x = (t >= o) ? s[t - o] : 0;
        __syncthreads();
        s[t] += x;
        __syncthreads();
    }
    int excl = s[t] - v + bsum[blockIdx.x];
    if (i < N) { rowptr[i] = excl; cursor[i] = excl; }
    if (i == N - 1) rowptr[N] = E;
}

__global__ __launch_bounds__(256) void scatter_sort(
    const int* __restrict__ src, const int* __restrict__ dst,
    const int* __restrict__ rel, int* __restrict__ cursor,
    int2* __restrict__ sedge, int E)
{
    int e = blockIdx.x * 256 + threadIdx.x;
    if (e >= E) return;
    int d = dst[e];
    int pos = atomicAdd(&cursor[d], 1);
    sedge[pos] = make_int2(src[e], rel[e]);
}

// One wave per dst node: walk edge segment, gather h_bf[src] (256B, 1 dword/lane),
// accumulate 4 per-basis pairs/lane, scale by norm, store bf16 A-panel row.
__global__ __launch_bounds__(256) void aggregate_pre(
    const unsigned short* __restrict__ hbf,   // (N,128) bf16
    const int* __restrict__ rowptr,
    const int2* __restrict__ sedge,
    const float* __restrict__ coeff,          // (R,4) f32
    const float* __restrict__ norm,           // (N,) f32
    unsigned short* __restrict__ A2,          // (N,512) bf16 = [d][b*128+i]
    int N)
{
    const int wave = threadIdx.x >> 6;
    const int lane = threadIdx.x & 63;
    const int d = blockIdx.x * 4 + wave;
    if (d >= N) return;
    const int start = rowptr[d];
    const int end   = rowptr[d + 1];

    float a00 = 0.f, a01 = 0.f, a10 = 0.f, a11 = 0.f;
    float a20 = 0.f, a21 = 0.f, a30 = 0.f, a31 = 0.f;

    int i = start;
    for (; i + 2 <= end; i += 2) {
        int2 e0 = sedge[i];
        int2 e1 = sedge[i + 1];
        unsigned int u0 = ((const unsigned int*)(hbf + (size_t)e0.x * 128))[lane];
        unsigned int u1 = ((const unsigned int*)(hbf + (size_t)e1.x * 128))[lane];
        float4 c0 = *(const float4*)(coeff + (size_t)e0.y * 4);
        float4 c1 = *(const float4*)(coeff + (size_t)e1.y * 4);
        float h00 = bf2f(u0 & 0xffffu), h01 = bf2f(u0 >> 16);
        float h10 = bf2f(u1 & 0xffffu), h11 = bf2f(u1 >> 16);
        a00 += c0.x * h00; a01 += c0.x * h01;
        a10 += c0.y * h00; a11 += c0.y * h01;
        a20 += c0.z * h00; a21 += c0.z * h01;
        a30 += c0.w * h00; a31 += c0.w * h01;
        a00 += c1.x * h10; a01 += c1.x * h11;
        a10 += c1.y * h10; a11 += c1.y * h11;
        a20 += c1.z * h10; a21 += c1.z * h11;
        a30 += c1.w * h10; a31 += c1.w * h11;
    }
    if (i < end) {
        int2 e0 = sedge[i];
        unsigned int u0 = ((const unsigned int*)(hbf + (size_t)e0.x * 128))[lane];
        float4 c0 = *(const float4*)(coeff + (size_t)e0.y * 4);
        float h00 = bf2f(u0 & 0xffffu), h01 = bf2f(u0 >> 16);
        a00 += c0.x * h00; a01 += c0.x * h01;
        a10 += c0.y * h00; a11 += c0.y * h01;
        a20 += c0.z * h00; a21 += c0.z * h01;
        a30 += c0.w * h00; a31 += c0.w * h01;
    }

    const float nm = norm[d];
    unsigned short* row = A2 + (size_t)d * 512 + lane * 2;
    unsigned int p0 = (unsigned int)f2bf(a00 * nm) | ((unsigned int)f2bf(a01 * nm) << 16);
    unsigned int p1 = (unsigned int)f2bf(a10 * nm) | ((unsigned int)f2bf(a11 * nm) << 16);
    unsigned int p2 = (unsigned int)f2bf(a20 * nm) | ((unsigned int)f2bf(a21 * nm) << 16);
    unsigned int p3 = (unsigned int)f2bf(a30 * nm) | ((unsigned int)f2bf(a31 * nm) << 16);
    *(unsigned int*)(row)       = p0;
    *(unsigned int*)(row + 128) = p1;
    *(unsigned int*)(row + 256) = p2;
    *(unsigned int*)(row + 384) = p3;
}

// out = relu([A2 | h_bf] @ WT2^T), (N,640)@(640,128) bf16 MFMA GEMM.
// Block = 4 waves = 64 rows; single 128-col slab. A in regs (20 frags), B from L2.
__global__ __launch_bounds__(256) void final_gemm(
    const unsigned short* __restrict__ A2,    // (N,512) bf16
    const unsigned short* __restrict__ hbf,   // (N,128) bf16
    const unsigned short* __restrict__ WT2,   // (128,640) bf16 [col][k]
    float* __restrict__ out, int N)
{
    const int wave = threadIdx.x >> 6;
    const int lane = threadIdx.x & 63;
    const int quad = lane >> 4;
    const int low  = lane & 15;
    const int m0 = blockIdx.x * 64 + wave * 16;

    int row = m0 + low;
    if (row >= N) row = N - 1;            // clamp for load; store is guarded

    bf16x8 afrag[20];
#pragma unroll
    for (int kk = 0; kk < 16; ++kk)
        afrag[kk] = *(const bf16x8*)(A2 + (size_t)row * 512 + kk * 32 + quad * 8);
#pragma unroll
    for (int kk = 0; kk < 4; ++kk)
        afrag[16 + kk] = *(const bf16x8*)(hbf + (size_t)row * 128 + kk * 32 + quad * 8);

    floatx4 acc[8];
#pragma unroll
    for (int t = 0; t < 8; ++t) acc[t] = (floatx4){0.f, 0.f, 0.f, 0.f};

#pragma unroll
    for (int t = 0; t < 8; ++t) {
        const unsigned short* bp = WT2 + (size_t)(t * 16 + low) * 640 + quad * 8;
#pragma unroll
        for (int kk = 0; kk < 20; ++kk) {
            acc[t] = __builtin_amdgcn_mfma_f32_16x16x32_bf16(
                afrag[kk], *(const bf16x8*)(bp + kk * 32), acc[t], 0, 0, 0);
        }
    }

    const int rbase = m0 + quad * 4;   // C/D: col=lane&15, row=(lane>>4)*4+reg
#pragma unroll
    for (int t = 0; t < 8; ++t) {
        const int c = t * 16 + low;
#pragma unroll
        for (int r = 0; r < 4; ++r) {
            int rr = rbase + r;
            if (rr >= N) continue;
            out[(size_t)rr * 128 + c] = fmaxf(acc[t][r], 0.f);
        }
    }
}

extern "C" void kernel_launch(void* const* d_in, const int* in_sizes, int n_in,
                              void* d_out, int out_size, void* d_ws, size_t ws_size,
                              hipStream_t stream)
{
    const float* h     = (const float*)d_in[0];
    const float* norm  = (const float*)d_in[1];
    const int*   src   = (const int*)d_in[2];
    const int*   dst   = (const int*)d_in[3];
    const int*   rel   = (const int*)d_in[4];
    const float* basis = (const float*)d_in[5];
    const float* coeff = (const float*)d_in[6];
    const float* loopw = (const float*)d_in[7];
    float* out = (float*)d_out;

    const int N = in_sizes[1];   // 50000
    const int E = in_sizes[2];   // 800000
    const int NB = (N + 255) / 256;   // 196 <= 256

    char* ws = (char*)d_ws;
    size_t off = 0;
    auto walloc = [&](size_t bytes) -> char* {
        char* p = ws + off;
        off = (off + bytes + 255) & ~(size_t)255;
        return p;
    };
    unsigned short* A2     = (unsigned short*)walloc((size_t)N * 512 * 2);  // 51.2 MB
    unsigned short* hbf    = (unsigned short*)walloc((size_t)N * 128 * 2);  // 12.8 MB
    unsigned short* WT2    = (unsigned short*)walloc(128 * 640 * 2);        // 164 KB
    int*            cnt    = (int*)walloc((size_t)N * 4);
    int*            rowptr = (int*)walloc((size_t)(N + 1) * 4);
    int*            cursor = (int*)walloc((size_t)N * 4);
    int*            bsum   = (int*)walloc((size_t)NB * 4);
    int2*           sedge  = (int2*)walloc((size_t)E * 8);                  // 6.4 MB

    hipMemsetAsync(cnt, 0, (size_t)N * 4, stream);
    conv_h<<<(N * 64 + 255) / 256, 256, 0, stream>>>(h, hbf, N);
    prep_wt2<<<128, 256, 0, stream>>>(basis, loopw, WT2);
    hist<<<(E + 255) / 256, 256, 0, stream>>>(dst, cnt, E);
    scan1<<<NB, 256, 0, stream>>>(cnt, bsum, N);
    scan2<<<1, 256, 0, stream>>>(bsum, NB);
    scan3<<<NB, 256, 0, stream>>>(cnt, bsum, rowptr, cursor, N, E);
    scatter_sort<<<(E + 255) / 256, 256, 0, stream>>>(src, dst, rel, cursor, sedge, E);
    aggregate_pre<<<(N + 3) / 4, 256, 0, stream>>>(hbf, rowptr, sedge, coeff, norm, A2, N);
    final_gemm<<<(N + 63) / 64, 256, 0, stream>>>(A2, hbf, WT2, out, N);
}

// Round 5
// 232.718 us; speedup vs baseline: 3.5995x; 1.4148x over previous
//
#include <hip/hip_runtime.h>

typedef short bf16x8 __attribute__((ext_vector_type(8)));
typedef float floatx4 __attribute__((ext_vector_type(4)));

typedef const __attribute__((address_space(1))) void* gas_ptr;
typedef __attribute__((address_space(3))) void* las_ptr;

__device__ __forceinline__ unsigned short f2bf(float f) {
    unsigned int u = __float_as_uint(f);
    unsigned int r = u + 0x7fffu + ((u >> 16) & 1u);   // RNE
    return (unsigned short)(r >> 16);
}
__device__ __forceinline__ float bf2f(unsigned int u) {
    return __uint_as_float(u << 16);
}

// Async global->LDS 16B: HW writes lbase + lane*16; g is the per-lane source.
__device__ __forceinline__ void stage16(const void* g, void* lbase, int lane) {
#if __has_builtin(__builtin_amdgcn_global_load_lds)
    __builtin_amdgcn_global_load_lds((gas_ptr)g, (las_ptr)lbase, 16, 0, 0);
#else
    *(float4*)((char*)lbase + lane * 16) = *(const float4*)g;
#endif
}

// h (N,128) f32 -> h_bf (N,128) bf16.
__global__ __launch_bounds__(256) void conv_h(
    const float* __restrict__ h, unsigned short* __restrict__ hbf, int N)
{
    int idx = blockIdx.x * 256 + threadIdx.x;
    if (idx >= N * 64) return;
    float2 v = *(const float2*)(h + (size_t)idx * 2);
    unsigned int pack = (unsigned int)f2bf(v.x) | ((unsigned int)f2bf(v.y) << 16);
    *(unsigned int*)(hbf + (size_t)idx * 2) = pack;
}

// WT2[col][k] bf16: k<512 -> basis[b=k>>7][i=k&127][col]; k>=512 -> loop_weight[k-512][col].
__global__ __launch_bounds__(256) void prep_wt2(
    const float* __restrict__ basis,
    const float* __restrict__ loopw,
    unsigned short* __restrict__ WT2)   // (128,640)
{
    int c = blockIdx.x;
    for (int k = threadIdx.x; k < 640; k += 256) {
        float v;
        if (k < 512) v = basis[(size_t)k * 128 + c];
        else         v = loopw[(size_t)(k - 512) * 128 + c];
        WT2[(size_t)c * 640 + k] = f2bf(v);
    }
}

// ---- counting sort by dst (no second atomic pass: hist returns stable slot) ----

__global__ __launch_bounds__(256) void hist_pos(
    const int* __restrict__ dst, int* __restrict__ cnt,
    int* __restrict__ pos, int E)
{
    int e = blockIdx.x * 256 + threadIdx.x;
    if (e < E) pos[e] = atomicAdd(&cnt[dst[e]], 1);
}

__global__ __launch_bounds__(256) void scan1(
    const int* __restrict__ cnt, int* __restrict__ bsum, int N)
{
    __shared__ int s[256];
    int i = blockIdx.x * 256 + threadIdx.x;
    int t = threadIdx.x;
    s[t] = (i < N) ? cnt[i] : 0;
    __syncthreads();
    for (int o = 128; o > 0; o >>= 1) {
        if (t < o) s[t] += s[t + o];
        __syncthreads();
    }
    if (t == 0) bsum[blockIdx.x] = s[0];
}

__global__ __launch_bounds__(256) void scan2(int* __restrict__ bsum, int nb)
{
    __shared__ int s[256];
    int t = threadIdx.x;
    int v = (t < nb) ? bsum[t] : 0;
    s[t] = v;
    __syncthreads();
    for (int o = 1; o < 256; o <<= 1) {
        int x = (t >= o) ? s[t - o] : 0;
        __syncthreads();
        s[t] += x;
        __syncthreads();
    }
    if (t < nb) bsum[t] = s[t] - v;   // exclusive
}

__global__ __launch_bounds__(256) void scan3(
    const int* __restrict__ cnt, const int* __restrict__ bsum,
    int* __restrict__ rowptr, int N, int E)
{
    __shared__ int s[256];
    int i = blockIdx.x * 256 + threadIdx.x;
    int t = threadIdx.x;
    int v = (i < N) ? cnt[i] : 0;
    s[t] = v;
    __syncthreads();
    for (int o = 1; o < 256; o <<= 1) {
        int x = (t >= o) ? s[t - o] : 0;
        __syncthreads();
        s[t] += x;
        __syncthreads();
    }
    int excl = s[t] - v + bsum[blockIdx.x];
    if (i < N) rowptr[i] = excl;
    if (i == N - 1) rowptr[N] = E;
}

// Packed edge: src (17 bits) | rel<<17. Valid for N<=131072, R<=128 (50000/100 here).
__global__ __launch_bounds__(256) void scatter_edges(
    const int* __restrict__ src, const int* __restrict__ dst,
    const int* __restrict__ rel, const int* __restrict__ rowptr,
    const int* __restrict__ pos, unsigned int* __restrict__ sedge, int E)
{
    int e = blockIdx.x * 256 + threadIdx.x;
    if (e >= E) return;
    int d = dst[e];
    sedge[rowptr[d] + pos[e]] = (unsigned int)src[e] | ((unsigned int)rel[e] << 17);
}

// One wave per dst: gather h_bf[src] (256B, 1 dword/lane), accumulate 4 basis
// pairs/lane, scale by norm, store bf16 A-panel row. Unroll 4 for MLP.
__global__ __launch_bounds__(256) void aggregate_pre(
    const unsigned short* __restrict__ hbf,
    const int* __restrict__ rowptr,
    const unsigned int* __restrict__ sedge,
    const float* __restrict__ coeff,
    const float* __restrict__ norm,
    unsigned short* __restrict__ A2, int N)
{
    const int wave = threadIdx.x >> 6;
    const int lane = threadIdx.x & 63;
    const int d = blockIdx.x * 4 + wave;
    if (d >= N) return;
    const int start = rowptr[d];
    const int end   = rowptr[d + 1];

    float a00 = 0.f, a01 = 0.f, a10 = 0.f, a11 = 0.f;
    float a20 = 0.f, a21 = 0.f, a30 = 0.f, a31 = 0.f;

    int i = start;
    for (; i + 4 <= end; i += 4) {
        unsigned int v0 = sedge[i],     v1 = sedge[i + 1];
        unsigned int v2 = sedge[i + 2], v3 = sedge[i + 3];
        unsigned int u0 = ((const unsigned int*)(hbf + (size_t)(v0 & 0x1ffffu) * 128))[lane];
        unsigned int u1 = ((const unsigned int*)(hbf + (size_t)(v1 & 0x1ffffu) * 128))[lane];
        unsigned int u2 = ((const unsigned int*)(hbf + (size_t)(v2 & 0x1ffffu) * 128))[lane];
        unsigned int u3 = ((const unsigned int*)(hbf + (size_t)(v3 & 0x1ffffu) * 128))[lane];
        float4 c0 = *(const float4*)(coeff + (size_t)(v0 >> 17) * 4);
        float4 c1 = *(const float4*)(coeff + (size_t)(v1 >> 17) * 4);
        float4 c2 = *(const float4*)(coeff + (size_t)(v2 >> 17) * 4);
        float4 c3 = *(const float4*)(coeff + (size_t)(v3 >> 17) * 4);
        float h00 = bf2f(u0 & 0xffffu), h01 = bf2f(u0 >> 16);
        float h10 = bf2f(u1 & 0xffffu), h11 = bf2f(u1 >> 16);
        float h20 = bf2f(u2 & 0xffffu), h21 = bf2f(u2 >> 16);
        float h30 = bf2f(u3 & 0xffffu), h31 = bf2f(u3 >> 16);
        a00 += c0.x * h00; a01 += c0.x * h01;
        a10 += c0.y * h00; a11 += c0.y * h01;
        a20 += c0.z * h00; a21 += c0.z * h01;
        a30 += c0.w * h00; a31 += c0.w * h01;
        a00 += c1.x * h10; a01 += c1.x * h11;
        a10 += c1.y * h10; a11 += c1.y * h11;
        a20 += c1.z * h10; a21 += c1.z * h11;
        a30 += c1.w * h10; a31 += c1.w * h11;
        a00 += c2.x * h20; a01 += c2.x * h21;
        a10 += c2.y * h20; a11 += c2.y * h21;
        a20 += c2.z * h20; a21 += c2.z * h21;
        a30 += c2.w * h20; a31 += c2.w * h21;
        a00 += c3.x * h30; a01 += c3.x * h31;
        a10 += c3.y * h30; a11 += c3.y * h31;
        a20 += c3.z * h30; a21 += c3.z * h31;
        a30 += c3.w * h30; a31 += c3.w * h31;
    }
    for (; i < end; ++i) {
        unsigned int v0 = sedge[i];
        unsigned int u0 = ((const unsigned int*)(hbf + (size_t)(v0 & 0x1ffffu) * 128))[lane];
        float4 c0 = *(const float4*)(coeff + (size_t)(v0 >> 17) * 4);
        float h00 = bf2f(u0 & 0xffffu), h01 = bf2f(u0 >> 16);
        a00 += c0.x * h00; a01 += c0.x * h01;
        a10 += c0.y * h00; a11 += c0.y * h01;
        a20 += c0.z * h00; a21 += c0.z * h01;
        a30 += c0.w * h00; a31 += c0.w * h01;
    }

    const float nm = norm[d];
    unsigned short* row = A2 + (size_t)d * 512 + lane * 2;
    *(unsigned int*)(row)       = (unsigned int)f2bf(a00 * nm) | ((unsigned int)f2bf(a01 * nm) << 16);
    *(unsigned int*)(row + 128) = (unsigned int)f2bf(a10 * nm) | ((unsigned int)f2bf(a11 * nm) << 16);
    *(unsigned int*)(row + 256) = (unsigned int)f2bf(a20 * nm) | ((unsigned int)f2bf(a21 * nm) << 16);
    *(unsigned int*)(row + 384) = (unsigned int)f2bf(a30 * nm) | ((unsigned int)f2bf(a31 * nm) << 16);
}

// out = relu([A2 | h_bf] @ WT2^T): (N,640)@(640,128), LDS-tiled MFMA GEMM.
// Block = 128 rows x 128 cols, BK=64, global_load_lds staging, [kc][row] k-major
// LDS layout (16B lane stride -> conflict-free ds_read_b128).
__global__ __launch_bounds__(256) void final_gemm(
    const unsigned short* __restrict__ A2,    // (N,512) bf16
    const unsigned short* __restrict__ hbf,   // (N,128) bf16
    const unsigned short* __restrict__ WT2,   // (128,640) bf16 [col][k]
    float* __restrict__ out, int N)
{
    __shared__ char sA[16384];   // [kc 0..7][row 0..127] x 16B
    __shared__ char sB[16384];   // [kc 0..7][col 0..127] x 16B
    const int t = threadIdx.x;
    const int w = t >> 6;
    const int lane = t & 63;
    const int quad = lane >> 4;
    const int low  = lane & 15;
    const int wr = w >> 1, wc = w & 1;   // 2x2 wave grid of 64x64 sub-tiles
    const int m0 = blockIdx.x * 128;

    floatx4 acc[4][4];
#pragma unroll
    for (int mt = 0; mt < 4; ++mt)
#pragma unroll
        for (int nt = 0; nt < 4; ++nt) acc[mt][nt] = (floatx4){0.f, 0.f, 0.f, 0.f};

    for (int it = 0; it < 10; ++it) {
        const int k0 = it * 64;
#pragma unroll
        for (int i = 0; i < 4; ++i) {
            const int slot = i * 256 + t;          // 0..1023
            const int kc  = slot >> 7;             // 0..7
            const int idx = slot & 127;            // row / col
            int grow = m0 + idx;
            if (grow >= N) grow = N - 1;           // clamp loads; stores guarded
            const unsigned short* gA = (k0 < 512)
                ? A2  + (size_t)grow * 512 + k0 + kc * 8
                : hbf + (size_t)grow * 128 + (k0 - 512) + kc * 8;
            const unsigned short* gB = WT2 + (size_t)idx * 640 + k0 + kc * 8;
            char* lbase = (char*)((i * 256 + w * 64) * 16);   // wave-uniform base
            stage16(gA, sA + (size_t)(i * 256 + w * 64) * 16, lane);
            stage16(gB, sB + (size_t)(i * 256 + w * 64) * 16, lane);
            (void)lbase;
        }
        __syncthreads();

#pragma unroll
        for (int ks = 0; ks < 2; ++ks) {
            bf16x8 af[4], bf[4];
#pragma unroll
            for (int mt = 0; mt < 4; ++mt)
                af[mt] = *(const bf16x8*)(sA + (size_t)(((ks * 4 + quad) << 7) + wr * 64 + mt * 16 + low) * 16);
#pragma unroll
            for (int nt = 0; nt < 4; ++nt)
                bf[nt] = *(const bf16x8*)(sB + (size_t)(((ks * 4 + quad) << 7) + wc * 64 + nt * 16 + low) * 16);
#pragma unroll
            for (int mt = 0; mt < 4; ++mt)
#pragma unroll
                for (int nt = 0; nt < 4; ++nt)
                    acc[mt][nt] = __builtin_amdgcn_mfma_f32_16x16x32_bf16(af[mt], bf[nt], acc[mt][nt], 0, 0, 0);
        }
        __syncthreads();
    }

    // C/D: col=lane&15, row=(lane>>4)*4+reg
#pragma unroll
    for (int mt = 0; mt < 4; ++mt) {
#pragma unroll
        for (int nt = 0; nt < 4; ++nt) {
            const int c = wc * 64 + nt * 16 + low;
#pragma unroll
            for (int r = 0; r < 4; ++r) {
                int rr = m0 + wr * 64 + mt * 16 + quad * 4 + r;
                if (rr < N) out[(size_t)rr * 128 + c] = fmaxf(acc[mt][nt][r], 0.f);
            }
        }
    }
}

extern "C" void kernel_launch(void* const* d_in, const int* in_sizes, int n_in,
                              void* d_out, int out_size, void* d_ws, size_t ws_size,
                              hipStream_t stream)
{
    const float* h     = (const float*)d_in[0];
    const float* norm  = (const float*)d_in[1];
    const int*   src   = (const int*)d_in[2];
    const int*   dst   = (const int*)d_in[3];
    const int*   rel   = (const int*)d_in[4];
    const float* basis = (const float*)d_in[5];
    const float* coeff = (const float*)d_in[6];
    const float* loopw = (const float*)d_in[7];
    float* out = (float*)d_out;

    const int N = in_sizes[1];   // 50000
    const int E = in_sizes[2];   // 800000
    const int NB = (N + 255) / 256;

    char* ws = (char*)d_ws;
    size_t off = 0;
    auto walloc = [&](size_t bytes) -> char* {
        char* p = ws + off;
        off = (off + bytes + 255) & ~(size_t)255;
        return p;
    };
    unsigned short* A2     = (unsigned short*)walloc((size_t)N * 512 * 2);  // 51.2 MB
    unsigned short* hbf    = (unsigned short*)walloc((size_t)N * 128 * 2);  // 12.8 MB
    unsigned short* WT2    = (unsigned short*)walloc(128 * 640 * 2);
    int*            cnt    = (int*)walloc((size_t)N * 4);
    int*            rowptr = (int*)walloc((size_t)(N + 1) * 4);
    int*            bsum   = (int*)walloc((size_t)NB * 4);
    int*            pos    = (int*)walloc((size_t)E * 4);                   // 3.2 MB
    unsigned int*   sedge  = (unsigned int*)walloc((size_t)E * 4);          // 3.2 MB

    hipMemsetAsync(cnt, 0, (size_t)N * 4, stream);
    conv_h<<<(N * 64 + 255) / 256, 256, 0, stream>>>(h, hbf, N);
    prep_wt2<<<128, 256, 0, stream>>>(basis, loopw, WT2);
    hist_pos<<<(E + 255) / 256, 256, 0, stream>>>(dst, cnt, pos, E);
    scan1<<<NB, 256, 0, stream>>>(cnt, bsum, N);
    scan2<<<1, 256, 0, stream>>>(bsum, NB);
    scan3<<<NB, 256, 0, stream>>>(cnt, bsum, rowptr, N, E);
    scatter_edges<<<(E + 255) / 256, 256, 0, stream>>>(src, dst, rel, rowptr, pos, sedge, E);
    aggregate_pre<<<(N + 3) / 4, 256, 0, stream>>>(hbf, rowptr, sedge, coeff, norm, A2, N);
    final_gemm<<<(N + 127) / 128, 256, 0, stream>>>(A2, hbf, WT2, out, N);
}

// Round 6
// 221.887 us; speedup vs baseline: 3.7751x; 1.0488x over previous
//
#include <hip/hip_runtime.h>

typedef short bf16x8 __attribute__((ext_vector_type(8)));
typedef float floatx4 __attribute__((ext_vector_type(4)));
typedef float floatx2 __attribute__((ext_vector_type(2)));

typedef const __attribute__((address_space(1))) void* gas_ptr;
typedef __attribute__((address_space(3))) void* las_ptr;

__device__ __forceinline__ unsigned short f2bf(float f) {
    unsigned int u = __float_as_uint(f);
    unsigned int r = u + 0x7fffu + ((u >> 16) & 1u);   // RNE
    return (unsigned short)(r >> 16);
}

// Async global->LDS 16B: HW writes lbase + lane*16; g is the per-lane source.
__device__ __forceinline__ void stage16(const void* g, void* lbase, int lane) {
#if __has_builtin(__builtin_amdgcn_global_load_lds)
    __builtin_amdgcn_global_load_lds((gas_ptr)g, (las_ptr)lbase, 16, 0, 0);
#else
    *(float4*)((char*)lbase + lane * 16) = *(const float4*)g;
#endif
}

// Fused prep: blocks [0,nb_conv) convert h->bf16; [nb_conv,nb_conv+nb_hist)
// histogram dst with stable slot return; last 128 blocks transpose weights.
__global__ __launch_bounds__(256) void prep_all(
    const float* __restrict__ h, unsigned short* __restrict__ hbf, int nconv,
    const int* __restrict__ dst, int* __restrict__ cnt, int* __restrict__ pos, int E,
    const float* __restrict__ basis, const float* __restrict__ loopw,
    unsigned short* __restrict__ WT2, int nb_conv, int nb_hist)
{
    int b = blockIdx.x;
    if (b < nb_conv) {
        int idx = b * 256 + threadIdx.x;
        if (idx < nconv) {
            float2 v = *(const float2*)(h + (size_t)idx * 2);
            unsigned int pack = (unsigned int)f2bf(v.x) | ((unsigned int)f2bf(v.y) << 16);
            *(unsigned int*)(hbf + (size_t)idx * 2) = pack;
        }
    } else if (b < nb_conv + nb_hist) {
        int e = (b - nb_conv) * 256 + threadIdx.x;
        if (e < E) pos[e] = atomicAdd(&cnt[dst[e]], 1);
    } else {
        int c = b - nb_conv - nb_hist;          // 0..127
        for (int k = threadIdx.x; k < 640; k += 256) {
            float v;
            if (k < 512) v = basis[(size_t)k * 128 + c];
            else         v = loopw[(size_t)(k - 512) * 128 + c];
            WT2[(size_t)c * 640 + k] = f2bf(v);
        }
    }
}

__global__ __launch_bounds__(256) void scan1(
    const int* __restrict__ cnt, int* __restrict__ bsum, int N)
{
    __shared__ int s[256];
    int i = blockIdx.x * 256 + threadIdx.x;
    int t = threadIdx.x;
    s[t] = (i < N) ? cnt[i] : 0;
    __syncthreads();
    for (int o = 128; o > 0; o >>= 1) {
        if (t < o) s[t] += s[t + o];
        __syncthreads();
    }
    if (t == 0) bsum[blockIdx.x] = s[0];
}

// Block-level scan + own block-prefix from bsum (requires gridDim.x <= 256).
__global__ __launch_bounds__(256) void scan_final(
    const int* __restrict__ cnt, const int* __restrict__ bsum,
    int* __restrict__ rowptr, int N, int E)
{
    __shared__ int s[256];
    __shared__ int sb[256];
    int t = threadIdx.x;
    int i = blockIdx.x * 256 + t;
    sb[t] = (t < (int)blockIdx.x) ? bsum[t] : 0;
    int v = (i < N) ? cnt[i] : 0;
    s[t] = v;
    __syncthreads();
    for (int o = 128; o > 0; o >>= 1) {        // reduce sb -> block prefix
        if (t < o) sb[t] += sb[t + o];
        __syncthreads();
    }
    for (int o = 1; o < 256; o <<= 1) {        // inclusive scan of s
        int x = (t >= o) ? s[t - o] : 0;
        __syncthreads();
        s[t] += x;
        __syncthreads();
    }
    int excl = s[t] - v + sb[0];
    if (i < N) rowptr[i] = excl;
    if (i == N - 1) rowptr[N] = E;
}

// Packed edge: (src<<8) | (rel<<25) — byte offset of h row + rel id.
// Valid for N<=65536, R<=128 (50000/100 here).
__global__ __launch_bounds__(256) void scatter_edges(
    const int* __restrict__ src, const int* __restrict__ dst,
    const int* __restrict__ rel, const int* __restrict__ rowptr,
    const int* __restrict__ pos, unsigned int* __restrict__ sedge, int E)
{
    int e = blockIdx.x * 256 + threadIdx.x;
    if (e >= E) return;
    int d = dst[e];
    sedge[rowptr[d] + pos[e]] = ((unsigned int)src[e] << 8) | ((unsigned int)rel[e] << 25);
}

// One wave per dst: gather h_bf[src] (256B, 1 dword/lane), accumulate 4 basis
// float2 pairs/lane (v_pk_fma_f32), scale by norm, store bf16 A-panel row.
// Coeffs in LDS; edge stream read as aligned uint4.
__global__ __launch_bounds__(256) void aggregate_pre(
    const unsigned short* __restrict__ hbf,
    const int* __restrict__ rowptr,
    const unsigned int* __restrict__ sedge,
    const float* __restrict__ coeff,
    const float* __restrict__ norm,
    unsigned short* __restrict__ A2, int N, int R)
{
    __shared__ float scoef[512];               // R*4 <= 512
    for (int i = threadIdx.x; i < R * 4; i += 256) scoef[i] = coeff[i];
    __syncthreads();

    const int wave = threadIdx.x >> 6;
    const int lane = threadIdx.x & 63;
    const int d = blockIdx.x * 4 + wave;
    if (d >= N) return;
    int i = rowptr[d];
    const int end = rowptr[d + 1];

    const char* hbase = (const char*)hbf + lane * 4;

    floatx2 a0 = {0.f, 0.f}, a1 = {0.f, 0.f}, a2 = {0.f, 0.f}, a3 = {0.f, 0.f};

#define EDGE_LOAD(v, u) \
    unsigned int u = *(const unsigned int*)(hbase + ((v) & 0x00FFFF00u));
#define EDGE_MATH(v, u) { \
    const float4 c = *(const float4*)((const char*)scoef + (((v) >> 25) << 4)); \
    floatx2 hp; \
    hp[0] = __uint_as_float((u) << 16); \
    hp[1] = __uint_as_float((u) & 0xFFFF0000u); \
    a0 = __builtin_elementwise_fma((floatx2){c.x, c.x}, hp, a0); \
    a1 = __builtin_elementwise_fma((floatx2){c.y, c.y}, hp, a1); \
    a2 = __builtin_elementwise_fma((floatx2){c.z, c.z}, hp, a2); \
    a3 = __builtin_elementwise_fma((floatx2){c.w, c.w}, hp, a3); }

    // align to 4-edge boundary (sedge 256B-aligned => uint4 loads aligned)
    while (i < end && (i & 3)) {
        unsigned int v = sedge[i];
        EDGE_LOAD(v, u)
        EDGE_MATH(v, u)
        ++i;
    }
    for (; i + 8 <= end; i += 8) {
        uint4 e0 = *(const uint4*)(sedge + i);
        uint4 e1 = *(const uint4*)(sedge + i + 4);
        EDGE_LOAD(e0.x, u0) EDGE_LOAD(e0.y, u1) EDGE_LOAD(e0.z, u2) EDGE_LOAD(e0.w, u3)
        EDGE_LOAD(e1.x, u4) EDGE_LOAD(e1.y, u5) EDGE_LOAD(e1.z, u6) EDGE_LOAD(e1.w, u7)
        EDGE_MATH(e0.x, u0) EDGE_MATH(e0.y, u1) EDGE_MATH(e0.z, u2) EDGE_MATH(e0.w, u3)
        EDGE_MATH(e1.x, u4) EDGE_MATH(e1.y, u5) EDGE_MATH(e1.z, u6) EDGE_MATH(e1.w, u7)
    }
    for (; i + 4 <= end; i += 4) {
        uint4 e0 = *(const uint4*)(sedge + i);
        EDGE_LOAD(e0.x, u0) EDGE_LOAD(e0.y, u1) EDGE_LOAD(e0.z, u2) EDGE_LOAD(e0.w, u3)
        EDGE_MATH(e0.x, u0) EDGE_MATH(e0.y, u1) EDGE_MATH(e0.z, u2) EDGE_MATH(e0.w, u3)
    }
    for (; i < end; ++i) {
        unsigned int v = sedge[i];
        EDGE_LOAD(v, u)
        EDGE_MATH(v, u)
    }
#undef EDGE_LOAD
#undef EDGE_MATH

    const float nm = norm[d];
    unsigned short* row = A2 + (size_t)d * 512 + lane * 2;
    *(unsigned int*)(row)       = (unsigned int)f2bf(a0[0] * nm) | ((unsigned int)f2bf(a0[1] * nm) << 16);
    *(unsigned int*)(row + 128) = (unsigned int)f2bf(a1[0] * nm) | ((unsigned int)f2bf(a1[1] * nm) << 16);
    *(unsigned int*)(row + 256) = (unsigned int)f2bf(a2[0] * nm) | ((unsigned int)f2bf(a2[1] * nm) << 16);
    *(unsigned int*)(row + 384) = (unsigned int)f2bf(a3[0] * nm) | ((unsigned int)f2bf(a3[1] * nm) << 16);
}

// out = relu([A2 | h_bf] @ WT2^T): (N,640)@(640,128), LDS-tiled MFMA GEMM.
__global__ __launch_bounds__(256) void final_gemm(
    const unsigned short* __restrict__ A2,    // (N,512) bf16
    const unsigned short* __restrict__ hbf,   // (N,128) bf16
    const unsigned short* __restrict__ WT2,   // (128,640) bf16 [col][k]
    float* __restrict__ out, int N)
{
    __shared__ char sA[16384];   // [kc 0..7][row 0..127] x 16B
    __shared__ char sB[16384];   // [kc 0..7][col 0..127] x 16B
    const int t = threadIdx.x;
    const int w = t >> 6;
    const int lane = t & 63;
    const int quad = lane >> 4;
    const int low  = lane & 15;
    const int wr = w >> 1, wc = w & 1;   // 2x2 wave grid of 64x64 sub-tiles
    const int m0 = blockIdx.x * 128;

    floatx4 acc[4][4];
#pragma unroll
    for (int mt = 0; mt < 4; ++mt)
#pragma unroll
        for (int nt = 0; nt < 4; ++nt) acc[mt][nt] = (floatx4){0.f, 0.f, 0.f, 0.f};

    for (int it = 0; it < 10; ++it) {
        const int k0 = it * 64;
#pragma unroll
        for (int i = 0; i < 4; ++i) {
            const int slot = i * 256 + t;          // 0..1023
            const int kc  = slot >> 7;             // 0..7
            const int idx = slot & 127;            // row / col
            int grow = m0 + idx;
            if (grow >= N) grow = N - 1;           // clamp loads; stores guarded
            const unsigned short* gA = (k0 < 512)
                ? A2  + (size_t)grow * 512 + k0 + kc * 8
                : hbf + (size_t)grow * 128 + (k0 - 512) + kc * 8;
            const unsigned short* gB = WT2 + (size_t)idx * 640 + k0 + kc * 8;
            stage16(gA, sA + (size_t)(i * 256 + w * 64) * 16, lane);
            stage16(gB, sB + (size_t)(i * 256 + w * 64) * 16, lane);
        }
        __syncthreads();

#pragma unroll
        for (int ks = 0; ks < 2; ++ks) {
            bf16x8 af[4], bfr[4];
#pragma unroll
            for (int mt = 0; mt < 4; ++mt)
                af[mt] = *(const bf16x8*)(sA + (size_t)(((ks * 4 + quad) << 7) + wr * 64 + mt * 16 + low) * 16);
#pragma unroll
            for (int nt = 0; nt < 4; ++nt)
                bfr[nt] = *(const bf16x8*)(sB + (size_t)(((ks * 4 + quad) << 7) + wc * 64 + nt * 16 + low) * 16);
#pragma unroll
            for (int mt = 0; mt < 4; ++mt)
#pragma unroll
                for (int nt = 0; nt < 4; ++nt)
                    acc[mt][nt] = __builtin_amdgcn_mfma_f32_16x16x32_bf16(af[mt], bfr[nt], acc[mt][nt], 0, 0, 0);
        }
        __syncthreads();
    }

    // C/D: col=lane&15, row=(lane>>4)*4+reg
#pragma unroll
    for (int mt = 0; mt < 4; ++mt) {
#pragma unroll
        for (int nt = 0; nt < 4; ++nt) {
            const int c = wc * 64 + nt * 16 + low;
#pragma unroll
            for (int r = 0; r < 4; ++r) {
                int rr = m0 + wr * 64 + mt * 16 + quad * 4 + r;
                if (rr < N) out[(size_t)rr * 128 + c] = fmaxf(acc[mt][nt][r], 0.f);
            }
        }
    }
}

extern "C" void kernel_launch(void* const* d_in, const int* in_sizes, int n_in,
                              void* d_out, int out_size, void* d_ws, size_t ws_size,
                              hipStream_t stream)
{
    const float* h     = (const float*)d_in[0];
    const float* norm  = (const float*)d_in[1];
    const int*   src   = (const int*)d_in[2];
    const int*   dst   = (const int*)d_in[3];
    const int*   rel   = (const int*)d_in[4];
    const float* basis = (const float*)d_in[5];
    const float* coeff = (const float*)d_in[6];
    const float* loopw = (const float*)d_in[7];
    float* out = (float*)d_out;

    const int N = in_sizes[1];       // 50000
    const int E = in_sizes[2];       // 800000
    const int R = in_sizes[6] / 4;   // 100
    const int NB = (N + 255) / 256;  // 196 <= 256

    char* ws = (char*)d_ws;
    size_t off = 0;
    auto walloc = [&](size_t bytes) -> char* {
        char* p = ws + off;
        off = (off + bytes + 255) & ~(size_t)255;
        return p;
    };
    unsigned short* A2     = (unsigned short*)walloc((size_t)N * 512 * 2);  // 51.2 MB
    unsigned short* hbf    = (unsigned short*)walloc((size_t)N * 128 * 2);  // 12.8 MB
    unsigned short* WT2    = (unsigned short*)walloc(128 * 640 * 2);
    int*            cnt    = (int*)walloc((size_t)N * 4);
    int*            rowptr = (int*)walloc((size_t)(N + 1) * 4);
    int*            bsum   = (int*)walloc((size_t)NB * 4);
    int*            pos    = (int*)walloc((size_t)E * 4);
    unsigned int*   sedge  = (unsigned int*)walloc((size_t)E * 4);

    const int nconv = N * 64;
    const int nb_conv = (nconv + 255) / 256;
    const int nb_hist = (E + 255) / 256;

    hipMemsetAsync(cnt, 0, (size_t)N * 4, stream);
    prep_all<<<nb_conv + nb_hist + 128, 256, 0, stream>>>(
        h, hbf, nconv, dst, cnt, pos, E, basis, loopw, WT2, nb_conv, nb_hist);
    scan1<<<NB, 256, 0, stream>>>(cnt, bsum, N);
    scan_final<<<NB, 256, 0, stream>>>(cnt, bsum, rowptr, N, E);
    scatter_edges<<<(E + 255) / 256, 256, 0, stream>>>(src, dst, rel, rowptr, pos, sedge, E);
    aggregate_pre<<<(N + 3) / 4, 256, 0, stream>>>(hbf, rowptr, sedge, coeff, norm, A2, N, R);
    final_gemm<<<(N + 127) / 128, 256, 0, stream>>>(A2, hbf, WT2, out, N);
}